// Round 15
// baseline (70.854 us; speedup 1.0000x reference)
//
#include <hip/hip_runtime.h>
#include <cstdint>
#include <cstddef>

#define N 8192
#define IN_F 256
#define OUT_F 128
#define ALPHA 0.2f
#define CAP 256
typedef unsigned long long ull;
typedef float f32x4 __attribute__((ext_vector_type(4)));

__device__ __forceinline__ float bf2f(unsigned short u) {
    return __uint_as_float(((unsigned)u) << 16);
}
__device__ __forceinline__ unsigned short f2bf(float f) {
    unsigned x = __float_as_uint(f);
    unsigned r = (x + 0x7FFFu + ((x >> 16) & 1u)) >> 16;   // round-nearest-even
    return (unsigned short)r;
}
__device__ __forceinline__ float lrelu(float e) { return e > 0.f ? e : ALPHA * e; }

// ---------------------------------------------------------------------------
// PRIMARY: one cooperative kernel, grid 2048 x 256 (32 waves/CU).
//  blocks 0..511: 16-row gemm tile -> hb/s1/s2 -> fence -> release add(done).
//  ALL blocks, per wave (1 wave = 1 row): chunked scan with INLINE max-free
//  gather: compact chunk b's hits to a per-wave LDS list, then (once the
//  done-flag is seen; checked once per chunk, no blocking) drain the backlog
//  in batches of 4 with independent s2[j]/hb[j] L2 loads — the gather hides
//  inside each chunk's HBM wait instead of convoying at kernel end.
//  No softmax phase, no weight storage: acc += exp(lrelu(si+s2[j])) * h[j],
//  dp += w (uniform across lanes). Epilogue: out = ELU(acc/dp).
// ---------------------------------------------------------------------------
__global__ __launch_bounds__(256, 8) void gat_all(const float* __restrict__ adj,
                                                  const float* __restrict__ x,
                                                  const float* __restrict__ W,
                                                  const float* __restrict__ a,
                                                  unsigned short* __restrict__ hb,
                                                  float* __restrict__ s1,
                                                  float* __restrict__ s2,
                                                  int* done,
                                                  float* __restrict__ out) {
    __shared__ __align__(16) float smem[4736];   // 18944 B union (gemm | lists)
    const int tid  = threadIdx.x;
    const int wv   = tid >> 6;
    const int lane = tid & 63;
    const int bid  = blockIdx.x;

    // ------------------------- gemm phase (blocks 0..511) -------------------
    if (bid < 512) {
        float* xsT = smem;          // [32][20] pad stride 20
        float* wsh = smem + 640;    // [32][128]
        const int R0 = bid * 16;
        const int r0 = (tid >> 5) * 2;
        const int c0 = (tid & 31) * 4;

        float acc[2][4];
#pragma unroll
        for (int r = 0; r < 2; ++r)
#pragma unroll
            for (int c = 0; c < 4; ++c) acc[r][c] = 0.f;

        for (int k0 = 0; k0 < IN_F; k0 += 32) {
            if (tid < 128) {
                const int r  = tid >> 3;
                const int k4 = tid & 7;
                const float4 v = *(const float4*)(x + (size_t)(R0 + r) * IN_F + k0 + k4 * 4);
                xsT[(k4 * 4 + 0) * 20 + r] = v.x;
                xsT[(k4 * 4 + 1) * 20 + r] = v.y;
                xsT[(k4 * 4 + 2) * 20 + r] = v.z;
                xsT[(k4 * 4 + 3) * 20 + r] = v.w;
            }
#pragma unroll
            for (int q = 0; q < 4; ++q) {
                const int f = tid + q * 256;
                *(float4*)(wsh + f * 4) = *(const float4*)(W + (size_t)k0 * OUT_F + f * 4);
            }
            __syncthreads();
#pragma unroll 8
            for (int kk = 0; kk < 32; ++kk) {
                const float4 wv4 = *(const float4*)(wsh + kk * 128 + c0);
                const float2 xv  = *(const float2*)(xsT + kk * 20 + r0);
                acc[0][0] += xv.x * wv4.x; acc[0][1] += xv.x * wv4.y; acc[0][2] += xv.x * wv4.z; acc[0][3] += xv.x * wv4.w;
                acc[1][0] += xv.y * wv4.x; acc[1][1] += xv.y * wv4.y; acc[1][2] += xv.y * wv4.z; acc[1][3] += xv.y * wv4.w;
            }
            __syncthreads();
        }

#pragma unroll
        for (int r = 0; r < 2; ++r) {
            ushort4 o4;
            o4.x = f2bf(acc[r][0]); o4.y = f2bf(acc[r][1]);
            o4.z = f2bf(acc[r][2]); o4.w = f2bf(acc[r][3]);
            *(ushort4*)(hb + (size_t)(R0 + r0 + r) * OUT_F + c0) = o4;
        }
        const float4 a1v = *(const float4*)(a + c0);
        const float4 a2v = *(const float4*)(a + OUT_F + c0);
#pragma unroll
        for (int r = 0; r < 2; ++r) {
            float p1 = acc[r][0] * a1v.x + acc[r][1] * a1v.y + acc[r][2] * a1v.z + acc[r][3] * a1v.w;
            float p2 = acc[r][0] * a2v.x + acc[r][1] * a2v.y + acc[r][2] * a2v.z + acc[r][3] * a2v.w;
#pragma unroll
            for (int off = 16; off > 0; off >>= 1) {
                p1 += __shfl_xor(p1, off);
                p2 += __shfl_xor(p2, off);
            }
            if ((tid & 31) == 0) {
                s1[R0 + r0 + r] = p1;
                s2[R0 + r0 + r] = p2;
            }
        }
        __threadfence();
        __syncthreads();
        if (tid == 0)
            __hip_atomic_fetch_add(done, 1, __ATOMIC_RELEASE, __HIP_MEMORY_SCOPE_AGENT);
    }

    // ------------------- scan + inline gather (all blocks) ------------------
    int* jlw = ((int*)smem) + wv * CAP;       // 1 KB per wave (overlay)
    const int row = bid * 4 + wv;
    const f32x4* __restrict__ arow = (const f32x4*)(adj + (size_t)row * N);
    const unsigned* __restrict__ hb32 = (const unsigned*)hb;
    const ull below = (1ull << lane) - 1ull;

    bool ready = false;
    float si = 0.f;
    int tot = 0, proc = 0;
    float acc0 = 0.f, acc1 = 0.f, dp = 0.f;

    f32x4 va[4], vb[4];
#pragma unroll
    for (int u = 0; u < 4; ++u) va[u] = arow[lane + u * 64];

    for (int b = 0; b < 8; ++b) {
        if (b < 7) {
#pragma unroll
            for (int u = 0; u < 4; ++u) vb[u] = arow[lane + ((b + 1) * 4 + u) * 64];
        }
        // ---- compact chunk b
#pragma unroll
        for (int u = 0; u < 4; ++u) {
            const int jb = (((b * 4 + u) * 64) + lane) * 4;
            const float av[4] = {va[u].x, va[u].y, va[u].z, va[u].w};
#pragma unroll
            for (int c = 0; c < 4; ++c) {
                const bool hit = av[c] > 0.f;
                const ull m = __ballot(hit);
                if (m) {
                    const int base = tot;
                    tot += __popcll(m);
                    if (hit) {
                        const int p = base + __popcll(m & below);
                        if (p < CAP) jlw[p] = jb + c;
                    }
                }
            }
        }
        // ---- gate (once per chunk, non-blocking)
        if (!ready &&
            __hip_atomic_load(done, __ATOMIC_ACQUIRE, __HIP_MEMORY_SCOPE_AGENT) >= 512) {
            ready = true;
            si = s1[row];
        }
        // ---- drain backlog in batches of 4 (independent L2 loads)
        if (ready) {
            const int te = tot < CAP ? tot : CAP;
            while (proc + 4 <= te) {
                const int j0 = jlw[proc + 0], j1 = jlw[proc + 1];
                const int j2 = jlw[proc + 2], j3 = jlw[proc + 3];
                const float e0 = si + s2[j0], e1 = si + s2[j1];
                const float e2 = si + s2[j2], e3 = si + s2[j3];
                const unsigned g0 = hb32[(size_t)j0 * 64 + lane];
                const unsigned g1 = hb32[(size_t)j1 * 64 + lane];
                const unsigned g2 = hb32[(size_t)j2 * 64 + lane];
                const unsigned g3 = hb32[(size_t)j3 * 64 + lane];
                const float w0 = __expf(lrelu(e0));
                const float w1 = __expf(lrelu(e1));
                const float w2 = __expf(lrelu(e2));
                const float w3 = __expf(lrelu(e3));
                acc0 += w0 * bf2f((unsigned short)(g0 & 0xFFFFu))
                      + w1 * bf2f((unsigned short)(g1 & 0xFFFFu))
                      + w2 * bf2f((unsigned short)(g2 & 0xFFFFu))
                      + w3 * bf2f((unsigned short)(g3 & 0xFFFFu));
                acc1 += w0 * bf2f((unsigned short)(g0 >> 16))
                      + w1 * bf2f((unsigned short)(g1 >> 16))
                      + w2 * bf2f((unsigned short)(g2 >> 16))
                      + w3 * bf2f((unsigned short)(g3 >> 16));
                dp += (w0 + w1) + (w2 + w3);
                proc += 4;
            }
        }
#pragma unroll
        for (int u = 0; u < 4; ++u) va[u] = vb[u];
    }

    // ---- ensure gemm published (long satisfied in practice)
    while (!ready) {
        if (__hip_atomic_load(done, __ATOMIC_ACQUIRE, __HIP_MEMORY_SCOPE_AGENT) >= 512) {
            ready = true;
            si = s1[row];
        } else {
            __builtin_amdgcn_s_sleep(2);
        }
    }
    // ---- flush remainder
    {
        const int te = tot < CAP ? tot : CAP;
        while (proc + 4 <= te) {
            const int j0 = jlw[proc + 0], j1 = jlw[proc + 1];
            const int j2 = jlw[proc + 2], j3 = jlw[proc + 3];
            const float e0 = si + s2[j0], e1 = si + s2[j1];
            const float e2 = si + s2[j2], e3 = si + s2[j3];
            const unsigned g0 = hb32[(size_t)j0 * 64 + lane];
            const unsigned g1 = hb32[(size_t)j1 * 64 + lane];
            const unsigned g2 = hb32[(size_t)j2 * 64 + lane];
            const unsigned g3 = hb32[(size_t)j3 * 64 + lane];
            const float w0 = __expf(lrelu(e0));
            const float w1 = __expf(lrelu(e1));
            const float w2 = __expf(lrelu(e2));
            const float w3 = __expf(lrelu(e3));
            acc0 += w0 * bf2f((unsigned short)(g0 & 0xFFFFu))
                  + w1 * bf2f((unsigned short)(g1 & 0xFFFFu))
                  + w2 * bf2f((unsigned short)(g2 & 0xFFFFu))
                  + w3 * bf2f((unsigned short)(g3 & 0xFFFFu));
            acc1 += w0 * bf2f((unsigned short)(g0 >> 16))
                  + w1 * bf2f((unsigned short)(g1 >> 16))
                  + w2 * bf2f((unsigned short)(g2 >> 16))
                  + w3 * bf2f((unsigned short)(g3 >> 16));
            dp += (w0 + w1) + (w2 + w3);
            proc += 4;
        }
        while (proc < te) {
            const int j = jlw[proc++];
            const float w = __expf(lrelu(si + s2[j]));
            const unsigned g = hb32[(size_t)j * 64 + lane];
            acc0 += w * bf2f((unsigned short)(g & 0xFFFFu));
            acc1 += w * bf2f((unsigned short)(g >> 16));
            dp += w;
        }
    }

    const float r = 1.f / dp;         // dp uniform across lanes; diag => dp>0
    float v0 = acc0 * r, v1 = acc1 * r;
    float2 o;
    o.x = v0 > 0.f ? v0 : (__expf(v0) - 1.f);
    o.y = v1 > 0.f ? v1 : (__expf(v1) - 1.f);
    *(float2*)(out + (size_t)row * OUT_F + 2 * lane) = o;
}

// ---------------------------------------------------------------------------
// FALLBACK (cooperative occupancy < 8 blocks/CU): proven R6 serial pair.
// ---------------------------------------------------------------------------
__global__ __launch_bounds__(256) void gemm_xw(const float* __restrict__ x,
                                               const float* __restrict__ W,
                                               const float* __restrict__ a,
                                               unsigned short* __restrict__ hb,
                                               float* __restrict__ s1,
                                               float* __restrict__ s2) {
    __shared__ __align__(16) float xsT[64 * 20];
    __shared__ __align__(16) float ws[64 * 128];
    const int tid = threadIdx.x;
    const int R0  = blockIdx.x * 16;
    const int r0  = (tid >> 5) * 2;
    const int c0  = (tid & 31) * 4;

    float acc[2][4];
#pragma unroll
    for (int r = 0; r < 2; ++r)
#pragma unroll
        for (int c = 0; c < 4; ++c) acc[r][c] = 0.f;

    for (int k0 = 0; k0 < IN_F; k0 += 64) {
        {
            const int r  = tid >> 4;
            const int k4 = tid & 15;
            const float4 v = *(const float4*)(x + (size_t)(R0 + r) * IN_F + k0 + k4 * 4);
            xsT[(k4 * 4 + 0) * 20 + r] = v.x;
            xsT[(k4 * 4 + 1) * 20 + r] = v.y;
            xsT[(k4 * 4 + 2) * 20 + r] = v.z;
            xsT[(k4 * 4 + 3) * 20 + r] = v.w;
        }
#pragma unroll
        for (int q = 0; q < 8; ++q) {
            const int f = tid + q * 256;
            *(float4*)(ws + f * 4) = *(const float4*)(W + (size_t)k0 * OUT_F + f * 4);
        }
        __syncthreads();
#pragma unroll 8
        for (int kk = 0; kk < 64; ++kk) {
            const float4 wv = *(const float4*)(ws + kk * 128 + c0);
            const float2 xv = *(const float2*)(xsT + kk * 20 + r0);
            acc[0][0] += xv.x * wv.x; acc[0][1] += xv.x * wv.y; acc[0][2] += xv.x * wv.z; acc[0][3] += xv.x * wv.w;
            acc[1][0] += xv.y * wv.x; acc[1][1] += xv.y * wv.y; acc[1][2] += xv.y * wv.z; acc[1][3] += xv.y * wv.w;
        }
        __syncthreads();
    }
#pragma unroll
    for (int r = 0; r < 2; ++r) {
        ushort4 o4;
        o4.x = f2bf(acc[r][0]); o4.y = f2bf(acc[r][1]);
        o4.z = f2bf(acc[r][2]); o4.w = f2bf(acc[r][3]);
        *(ushort4*)(hb + (size_t)(R0 + r0 + r) * OUT_F + c0) = o4;
    }
    const float4 a1v = *(const float4*)(a + c0);
    const float4 a2v = *(const float4*)(a + OUT_F + c0);
#pragma unroll
    for (int r = 0; r < 2; ++r) {
        float p1 = acc[r][0] * a1v.x + acc[r][1] * a1v.y + acc[r][2] * a1v.z + acc[r][3] * a1v.w;
        float p2 = acc[r][0] * a2v.x + acc[r][1] * a2v.y + acc[r][2] * a2v.z + acc[r][3] * a2v.w;
#pragma unroll
        for (int off = 16; off > 0; off >>= 1) {
            p1 += __shfl_xor(p1, off);
            p2 += __shfl_xor(p2, off);
        }
        if ((tid & 31) == 0) {
            s1[R0 + r0 + r] = p1;
            s2[R0 + r0 + r] = p2;
        }
    }
}

__global__ __launch_bounds__(256, 8) void gat_fused(const float* __restrict__ adj,
                                                    const unsigned short* __restrict__ hb,
                                                    const float* __restrict__ s1,
                                                    const float* __restrict__ s2,
                                                    float* __restrict__ out) {
    const int tid  = threadIdx.x;
    const int wv   = tid >> 6;
    const int lane = tid & 63;
    const int row  = blockIdx.x * 4 + wv;

    __shared__ int   jl[4][CAP];
    __shared__ float el[4][CAP];

    const f32x4* __restrict__ arow = (const f32x4*)(adj + (size_t)row * N);
    const ull below = (1ull << lane) - 1ull;

    int tot = 0;
    f32x4 va[4], vb[4];
#pragma unroll
    for (int u = 0; u < 4; ++u) va[u] = arow[lane + u * 64];

    for (int b = 0; b < 8; ++b) {
        if (b < 7) {
#pragma unroll
            for (int u = 0; u < 4; ++u) vb[u] = arow[lane + ((b + 1) * 4 + u) * 64];
        }
#pragma unroll
        for (int u = 0; u < 4; ++u) {
            const int jb = (((b * 4 + u) * 64) + lane) * 4;
            const float av[4] = {va[u].x, va[u].y, va[u].z, va[u].w};
#pragma unroll
            for (int c = 0; c < 4; ++c) {
                const bool hit = av[c] > 0.f;
                const ull m = __ballot(hit);
                if (m) {
                    const int base = tot;
                    tot += __popcll(m);
                    if (hit) {
                        const int p = base + __popcll(m & below);
                        if (p < CAP) jl[wv][p] = jb + c;
                    }
                }
            }
        }
#pragma unroll
        for (int u = 0; u < 4; ++u) va[u] = vb[u];
    }
    const int n = tot < CAP ? tot : CAP;

    const float si = s1[row];
    float dp = 0.f;
#pragma unroll
    for (int t = 0; t < 4; ++t) {
        const int l = lane + t * 64;
        if (l < n) {
            const float w = __expf(lrelu(si + s2[jl[wv][l]]));
            el[wv][l] = w;
            dp += w;
        }
    }
#pragma unroll
    for (int off = 32; off > 0; off >>= 1) dp += __shfl_xor(dp, off);
    const float denom = dp;

    const int half = lane >> 5;
    const int col4 = (lane & 31) * 4;
    float a0 = 0.f, a1 = 0.f, a2 = 0.f, a3 = 0.f;
#pragma unroll 4
    for (int l = half; l < n; l += 2) {
        const float wgt = el[wv][l];
        const int j = jl[wv][l];
        const ushort4 hv = *(const ushort4*)(hb + (size_t)j * OUT_F + col4);
        a0 += wgt * bf2f(hv.x);
        a1 += wgt * bf2f(hv.y);
        a2 += wgt * bf2f(hv.z);
        a3 += wgt * bf2f(hv.w);
    }
    a0 += __shfl_xor(a0, 32);
    a1 += __shfl_xor(a1, 32);
    a2 += __shfl_xor(a2, 32);
    a3 += __shfl_xor(a3, 32);

    if (half == 0) {
        const float r = 1.f / denom;
        float v0 = a0 * r, v1 = a1 * r, v2 = a2 * r, v3 = a3 * r;
        float4 o;
        o.x = v0 > 0.f ? v0 : (__expf(v0) - 1.f);
        o.y = v1 > 0.f ? v1 : (__expf(v1) - 1.f);
        o.z = v2 > 0.f ? v2 : (__expf(v2) - 1.f);
        o.w = v3 > 0.f ? v3 : (__expf(v3) - 1.f);
        *(float4*)(out + (size_t)row * OUT_F + col4) = o;
    }
}

// ---------------------------------------------------------------------------
extern "C" void kernel_launch(void* const* d_in, const int* in_sizes, int n_in,
                              void* d_out, int out_size, void* d_ws, size_t ws_size,
                              hipStream_t stream) {
    const float* x   = (const float*)d_in[0];   // (8192, 256)
    const float* adj = (const float*)d_in[1];   // (8192, 8192)
    const float* W   = (const float*)d_in[2];   // (256, 128)
    const float* a   = (const float*)d_in[3];   // (256, 1)
    float* out = (float*)d_out;                 // (8192, 128) fp32

    char* wsb = (char*)d_ws;
    unsigned short* hb = (unsigned short*)wsb;                    // 2 MB bf16 h
    float* s1 = (float*)(wsb + 2 * 1024 * 1024);                  // 32 KB
    float* s2 = s1 + N;                                           // 32 KB
    int* done = (int*)(wsb + 2 * 1024 * 1024 + 64 * 1024);        // 4 B flag

    int nb = 0;
    (void)hipOccupancyMaxActiveBlocksPerMultiprocessor(&nb, gat_all, 256, 0);
    if (nb >= 8) {
        hipMemsetAsync(done, 0, sizeof(int), stream);
        void* args[] = {(void*)&adj, (void*)&x, (void*)&W, (void*)&a,
                        (void*)&hb, (void*)&s1, (void*)&s2, (void*)&done, (void*)&out};
        hipLaunchCooperativeKernel((const void*)gat_all, dim3(2048), dim3(256),
                                   args, 0, stream);
    } else {
        gemm_xw<<<N / 16, 256, 0, stream>>>(x, W, a, hb, s1, s2);
        gat_fused<<<2048, 256, 0, stream>>>(adj, hb, s1, s2, out);
    }
}